// Round 2
// baseline (5623.631 us; speedup 1.0000x reference)
//
#include <hip/hip_runtime.h>
#include <math.h>

// RipsLayer: dim-0 persistence of Rips filtration on 4096 points in R^64.
// Phase 1: dense distance matrix D (64 MiB, in d_ws).
// Phase 2: exact Prim replay, software-pipelined:
//   next argmin = combine(m1 = argmin over old mind, m2 = argmin over new row)
//   -> m1 reduce hides under the row load; next vertex is always c1 or c2,
//      so row_{c1} is speculatively prefetched each step.

#define N 4096
#define DF 64
#define INF __builtin_huge_valf()

// ---------------------------------------------------------------------------
// Phase 1: D[i][j] = sqrt(max(|x_i - x_j|^2, 1e-12)), diag = +inf.
// ---------------------------------------------------------------------------
__global__ __launch_bounds__(256) void build_d_kernel(const float* __restrict__ x,
                                                      float* __restrict__ D) {
    __shared__ float As[64][68];
    __shared__ float Bs[64][68];
    const int bi = blockIdx.y * 64;
    const int bj = blockIdx.x * 64;
    const int t = threadIdx.x;

#pragma unroll
    for (int g = 0; g < 4; ++g) {
        int idx = t + 256 * g;
        int row = idx >> 4;
        int k4 = (idx & 15) << 2;
        float4 va = *(const float4*)(x + (size_t)(bi + row) * DF + k4);
        float4 vb = *(const float4*)(x + (size_t)(bj + row) * DF + k4);
        *(float4*)(&As[row][k4]) = va;
        *(float4*)(&Bs[row][k4]) = vb;
    }
    __syncthreads();

    const int ti = (t >> 4) << 2;
    const int tj = (t & 15) << 2;

    float acc[4][4];
#pragma unroll
    for (int r = 0; r < 4; ++r)
#pragma unroll
        for (int c = 0; c < 4; ++c) acc[r][c] = 0.0f;

    for (int k = 0; k < 64; k += 4) {
        float4 a[4], b[4];
#pragma unroll
        for (int r = 0; r < 4; ++r) a[r] = *(const float4*)(&As[ti + r][k]);
#pragma unroll
        for (int c = 0; c < 4; ++c) b[c] = *(const float4*)(&Bs[tj + c][k]);
#pragma unroll
        for (int r = 0; r < 4; ++r)
#pragma unroll
            for (int c = 0; c < 4; ++c) {
                float d0 = a[r].x - b[c].x;
                float d1 = a[r].y - b[c].y;
                float d2 = a[r].z - b[c].z;
                float d3 = a[r].w - b[c].w;
                float s = acc[r][c];
                s = fmaf(d0, d0, s);
                s = fmaf(d1, d1, s);
                s = fmaf(d2, d2, s);
                s = fmaf(d3, d3, s);
                acc[r][c] = s;
            }
    }

#pragma unroll
    for (int r = 0; r < 4; ++r) {
        int i = bi + ti + r;
        float4 v;
        float* vp = &v.x;
#pragma unroll
        for (int c = 0; c < 4; ++c) {
            int j = bj + tj + c;
            vp[c] = (i == j) ? INF : sqrtf(fmaxf(acc[r][c], 1e-12f));
        }
        *(float4*)(D + (size_t)i * N + (bj + tj)) = v;
    }
}

// ---------------------------------------------------------------------------
// Phase 2 helpers. Thread t owns columns [16t, 16t+16) -> col monotone in
// (wave, lane), so lowest-lane == lowest-col for the ballot tie-break.
// ---------------------------------------------------------------------------
__device__ __forceinline__ void load_row(float4 r[4], const float* __restrict__ D,
                                         int j, int t) {
    const float4* rp = (const float4*)(D + (size_t)(unsigned)j * N);
#pragma unroll
    for (int g = 0; g < 4; ++g) r[g] = rp[4 * t + g];
}

// Full (local tree -> wave butterfly+ballot -> LDS cross-wave) argmin.
// Returns uniform packed key: (f32 bits << 32) | col. Lowest value wins,
// ties -> lowest col (exact jnp.argmin semantics). Contains one barrier.
__device__ __forceinline__ unsigned long long argmin_reduce(
    const float4 v4[4], unsigned mask, int t, unsigned long long* part) {
    float va[16];
    int ia[16];
#pragma unroll
    for (int g = 0; g < 4; ++g) {
        const float* p = (const float*)&v4[g];
#pragma unroll
        for (int l = 0; l < 4; ++l) {
            int i = 4 * g + l;
            va[i] = ((mask >> i) & 1u) ? INF : p[l];
            ia[i] = i;
        }
    }
    // depth-4 tree; strict '<' on the higher index keeps lowest-col on ties
#pragma unroll
    for (int st = 1; st < 16; st <<= 1)
#pragma unroll
        for (int i = 0; i < 16; i += 2 * st)
            if (va[i + st] < va[i]) { va[i] = va[i + st]; ia[i] = ia[i + st]; }

    float lv = va[0];
    int lc = (t << 4) | ia[0];

    // value-only 64-lane butterfly
    float m = lv;
#pragma unroll
    for (int off = 1; off < 64; off <<= 1)
        m = fminf(m, __shfl_xor(m, off, 64));
    // index via ballot: lowest tied lane == lowest col (ownership is monotone)
    unsigned long long tied = __ballot(lv == m);
    int src = __ffsll((unsigned long long)tied) - 1;
    int wcol = __shfl(lc, src, 64);

    if ((t & 63) == 0)
        part[t >> 6] =
            ((unsigned long long)__float_as_uint(m) << 32) | (unsigned)wcol;
    __syncthreads();
    unsigned long long k = part[0];
#pragma unroll
    for (int w = 1; w < 4; ++w) {
        unsigned long long o = part[w];
        if (o < k) k = o;
    }
    return k;
}

__global__ __launch_bounds__(256) void prim_kernel(const float* __restrict__ D,
                                                   float* __restrict__ out) {
    __shared__ unsigned long long partA[4];
    __shared__ unsigned long long partB[4];
    const int t = threadIdx.x;

    float4 mind[4], rowA[4], rowB[4];
    unsigned mask = (t == 0) ? 1u : 0u;  // vertex 0 in tree (col 0 owned by t0)

    const float4* r0 = (const float4*)D;
#pragma unroll
    for (int g = 0; g < 4; ++g) mind[g] = r0[4 * t + g];  // row 0

    // ---- selection 1 (no row dependency) ----
    unsigned long long k1 = argmin_reduce(mind, mask, t, partA);
    int j = (int)(k1 & 0xffffffffULL);
    if (t == 0) {
        out[0] = 0.0f;
        out[1] = __uint_as_float((unsigned)(k1 >> 32));
    }
    if ((j >> 4) == t) mask |= 1u << (j & 15);
    load_row(rowA, D, j, t);  // row of selected vertex (in flight)

    // m1 over current mind (excl tree) — hidden under rowA's load latency
    unsigned long long m1 = argmin_reduce(mind, mask, t, partB);
    int specc = (int)(m1 & 0xffffffffULL);
    load_row(rowB, D, specc, t);  // speculative: next j is always c1 or c2

    // ---- selections 2..N-1 ----
    for (int s = 2; s < N; ++s) {
        // m2 over the just-arrived row (tree cols masked)
        unsigned long long m2 = argmin_reduce(rowA, mask, t, partA);
        unsigned long long kk = (m2 < m1) ? m2 : m1;  // tie -> lower col (low bits)
        j = (int)(kk & 0xffffffffULL);
        if (t == 0) {
            out[2 * (s - 1)] = 0.0f;
            out[2 * (s - 1) + 1] = __uint_as_float((unsigned)(kk >> 32));
        }

        // fold row into mind
#pragma unroll
        for (int g = 0; g < 4; ++g) {
            mind[g].x = fminf(mind[g].x, rowA[g].x);
            mind[g].y = fminf(mind[g].y, rowA[g].y);
            mind[g].z = fminf(mind[g].z, rowA[g].z);
            mind[g].w = fminf(mind[g].w, rowA[g].w);
        }
        if ((j >> 4) == t) mask |= 1u << (j & 15);

        // next consume row: speculation hit -> already loaded
        if (j == specc) {
#pragma unroll
            for (int g = 0; g < 4; ++g) rowA[g] = rowB[g];
        } else {
            load_row(rowA, D, j, t);
        }

        // m1' over updated mind — overlaps the rowA load; then re-speculate
        m1 = argmin_reduce(mind, mask, t, partB);
        specc = (int)(m1 & 0xffffffffULL);
        load_row(rowB, D, specc, t);
    }
}

// ---------------------------------------------------------------------------
extern "C" void kernel_launch(void* const* d_in, const int* in_sizes, int n_in,
                              void* d_out, int out_size, void* d_ws, size_t ws_size,
                              hipStream_t stream) {
    const float* x = (const float*)d_in[0];
    float* D = (float*)d_ws;     // requires ws_size >= N*N*4 = 64 MiB
    float* out = (float*)d_out;  // [N-1][2]: (birth=0, death)

    dim3 grid(N / 64, N / 64);
    build_d_kernel<<<grid, 256, 0, stream>>>(x, D);
    prim_kernel<<<1, 256, 0, stream>>>(D, out);
}

// Round 3
// 5145.602 us; speedup vs baseline: 1.0929x; 1.0929x over previous
//
#include <hip/hip_runtime.h>
#include <math.h>

// RipsLayer: dim-0 persistence of Rips filtration on 4096 points in R^64.
// Phase 1: dense distance matrix D (64 MiB, in d_ws).
// Phase 2: exact Prim replay, 1 workgroup / 4 waves:
//   - f32 value butterfly + ballot (lowest lane == lowest col, exact ties)
//   - ONE barrier per step (double-buffered partials, redundant combine)
//   - free runner-up speculation from the 4-way combine hides the row load

#define N 4096
#define DF 64
#define INF __builtin_huge_valf()

// ---------------------------------------------------------------------------
// Phase 1: D[i][j] = sqrt(max(|x_i - x_j|^2, 1e-12)), diag = +inf.
// ---------------------------------------------------------------------------
__global__ __launch_bounds__(256) void build_d_kernel(const float* __restrict__ x,
                                                      float* __restrict__ D) {
    __shared__ float As[64][68];
    __shared__ float Bs[64][68];
    const int bi = blockIdx.y * 64;
    const int bj = blockIdx.x * 64;
    const int t = threadIdx.x;

#pragma unroll
    for (int g = 0; g < 4; ++g) {
        int idx = t + 256 * g;
        int row = idx >> 4;
        int k4 = (idx & 15) << 2;
        float4 va = *(const float4*)(x + (size_t)(bi + row) * DF + k4);
        float4 vb = *(const float4*)(x + (size_t)(bj + row) * DF + k4);
        *(float4*)(&As[row][k4]) = va;
        *(float4*)(&Bs[row][k4]) = vb;
    }
    __syncthreads();

    const int ti = (t >> 4) << 2;
    const int tj = (t & 15) << 2;

    float acc[4][4];
#pragma unroll
    for (int r = 0; r < 4; ++r)
#pragma unroll
        for (int c = 0; c < 4; ++c) acc[r][c] = 0.0f;

    for (int k = 0; k < 64; k += 4) {
        float4 a[4], b[4];
#pragma unroll
        for (int r = 0; r < 4; ++r) a[r] = *(const float4*)(&As[ti + r][k]);
#pragma unroll
        for (int c = 0; c < 4; ++c) b[c] = *(const float4*)(&Bs[tj + c][k]);
#pragma unroll
        for (int r = 0; r < 4; ++r)
#pragma unroll
            for (int c = 0; c < 4; ++c) {
                float d0 = a[r].x - b[c].x;
                float d1 = a[r].y - b[c].y;
                float d2 = a[r].z - b[c].z;
                float d3 = a[r].w - b[c].w;
                float s = acc[r][c];
                s = fmaf(d0, d0, s);
                s = fmaf(d1, d1, s);
                s = fmaf(d2, d2, s);
                s = fmaf(d3, d3, s);
                acc[r][c] = s;
            }
    }

#pragma unroll
    for (int r = 0; r < 4; ++r) {
        int i = bi + ti + r;
        float4 v;
        float* vp = &v.x;
#pragma unroll
        for (int c = 0; c < 4; ++c) {
            int j = bj + tj + c;
            vp[c] = (i == j) ? INF : sqrtf(fmaxf(acc[r][c], 1e-12f));
        }
        *(float4*)(D + (size_t)i * N + (bj + tj)) = v;
    }
}

// ---------------------------------------------------------------------------
// Phase 2: thread t owns cols [16t, 16t+16) — col strictly monotone in t,
// so lowest tied lane == lowest col and cross-wave u64 min == lowest col.
// ---------------------------------------------------------------------------
__global__ __launch_bounds__(256) void prim_kernel(const float* __restrict__ D,
                                                   float* __restrict__ out) {
    __shared__ unsigned long long part[2][4];  // double-buffered wave winners
    const int t = threadIdx.x;
    const int lane = t & 63;
    const int wv = t >> 6;

    float4 mind[4];
    const float4* r0 = (const float4*)D;
#pragma unroll
    for (int q = 0; q < 4; ++q) mind[q] = r0[4 * t + q];  // row 0 (D[0][0]=INF)

    unsigned mask = (t == 0) ? 1u : 0u;  // vertex 0 in tree

    float4 pre[4];   // speculative row (runner-up of previous combine)
    int c2prev = -1;

    for (int s = 1; s < N; ++s) {
        // ---- masked values + lane min ----
        float mk[16];
#pragma unroll
        for (int q = 0; q < 4; ++q) {
            const float* p = (const float*)&mind[q];
#pragma unroll
            for (int c = 0; c < 4; ++c) {
                int i = 4 * q + c;
                mk[i] = ((mask >> i) & 1u) ? INF : p[c];
            }
        }
        float lm = mk[0];
#pragma unroll
        for (int i = 1; i < 16; ++i) lm = fminf(lm, mk[i]);

        // ---- wave min (value-only butterfly) ----
        float wm = lm;
#pragma unroll
        for (int off = 1; off < 64; off <<= 1)
            wm = fminf(wm, __shfl_xor(wm, off, 64));

        // ---- wave winner lane & its (lowest) column ----
        unsigned long long tied = __ballot(lm == wm);
        int wlane = __ffsll(tied) - 1;
        int sel = 0;
#pragma unroll
        for (int i = 15; i >= 0; --i)   // descending: lowest matching i wins
            if (mk[i] == wm) sel = i;
        int mycol = (t << 4) | sel;
        int wcol = __shfl(mycol, wlane, 64);

        // ---- cross-wave combine (one barrier, double-buffered) ----
        const int pb = s & 1;
        if (lane == 0)
            part[pb][wv] = ((unsigned long long)__float_as_uint(wm) << 32) |
                           (unsigned)wcol;
        __syncthreads();
        unsigned long long k0 = part[pb][0], k1 = part[pb][1];
        unsigned long long k2 = part[pb][2], k3 = part[pb][3];
        unsigned long long m01 = k0 < k1 ? k0 : k1, M01 = k0 < k1 ? k1 : k0;
        unsigned long long m23 = k2 < k3 ? k2 : k3, M23 = k2 < k3 ? k3 : k2;
        unsigned long long best = m01 < m23 ? m01 : m23;
        unsigned long long mxw  = m01 < m23 ? M01 : M23;  // runner in winning pair
        unsigned long long mnl  = m01 < m23 ? m23 : m01;  // min of losing pair
        unsigned long long sec  = mxw < mnl ? mxw : mnl;  // 2nd best of 4 waves
        int j  = (int)(best & 0xffffffffULL);
        int c2 = (int)(sec & 0xffffffffULL);

        if (t == 0) {
            out[2 * (s - 1)] = 0.0f;
            out[2 * (s - 1) + 1] = __uint_as_float((unsigned)(best >> 32));
        }
        if ((j >> 4) == t) mask |= 1u << (j & 15);  // owner marks in-tree

        // ---- consume row j: speculation hit -> already in flight ----
        float4 rowv[4];
        if (j == c2prev) {
#pragma unroll
            for (int q = 0; q < 4; ++q) rowv[q] = pre[q];
        } else {
            const float4* rp = (const float4*)(D + (size_t)(unsigned)j * N);
#pragma unroll
            for (int q = 0; q < 4; ++q) rowv[q] = rp[4 * t + q];
        }

        // ---- re-speculate: prefetch runner-up row for next step ----
        {
            const float4* sp = (const float4*)(D + (size_t)(unsigned)c2 * N);
#pragma unroll
            for (int q = 0; q < 4; ++q) pre[q] = sp[4 * t + q];
            c2prev = c2;
        }

        // ---- fold ----
#pragma unroll
        for (int q = 0; q < 4; ++q) {
            mind[q].x = fminf(mind[q].x, rowv[q].x);
            mind[q].y = fminf(mind[q].y, rowv[q].y);
            mind[q].z = fminf(mind[q].z, rowv[q].z);
            mind[q].w = fminf(mind[q].w, rowv[q].w);
        }
    }
}

// ---------------------------------------------------------------------------
extern "C" void kernel_launch(void* const* d_in, const int* in_sizes, int n_in,
                              void* d_out, int out_size, void* d_ws, size_t ws_size,
                              hipStream_t stream) {
    const float* x = (const float*)d_in[0];
    float* D = (float*)d_ws;     // requires ws_size >= N*N*4 = 64 MiB
    float* out = (float*)d_out;  // [N-1][2]: (birth=0, death)

    dim3 grid(N / 64, N / 64);
    build_d_kernel<<<grid, 256, 0, stream>>>(x, D);
    prim_kernel<<<1, 256, 0, stream>>>(D, out);
}

// Round 4
// 4659.941 us; speedup vs baseline: 1.2068x; 1.1042x over previous
//
#include <hip/hip_runtime.h>
#include <math.h>

// RipsLayer: dim-0 persistence of Rips filtration on 4096 points in R^64.
// Phase 1: dense distance matrix D (64 MiB, in d_ws).
// Phase 2: exact Prim replay, 1 workgroup / 4 waves:
//   - u64 (value<<32|col) butterfly -> exact lowest-col tie-break
//   - barrier WITHOUT vmcnt drain (asm s_waitcnt lgkmcnt(0) + s_barrier)
//     so speculative row prefetches survive across steps
//   - runner-up speculation from the 4-way wave combine hides the row load

#define N 4096
#define DF 64
#define INF __builtin_huge_valf()

// ---------------------------------------------------------------------------
// Phase 1: D[i][j] = sqrt(max(|x_i - x_j|^2, 1e-12)), diag = +inf.
// ---------------------------------------------------------------------------
__global__ __launch_bounds__(256) void build_d_kernel(const float* __restrict__ x,
                                                      float* __restrict__ D) {
    __shared__ float As[64][68];
    __shared__ float Bs[64][68];
    const int bi = blockIdx.y * 64;
    const int bj = blockIdx.x * 64;
    const int t = threadIdx.x;

#pragma unroll
    for (int g = 0; g < 4; ++g) {
        int idx = t + 256 * g;
        int row = idx >> 4;
        int k4 = (idx & 15) << 2;
        float4 va = *(const float4*)(x + (size_t)(bi + row) * DF + k4);
        float4 vb = *(const float4*)(x + (size_t)(bj + row) * DF + k4);
        *(float4*)(&As[row][k4]) = va;
        *(float4*)(&Bs[row][k4]) = vb;
    }
    __syncthreads();

    const int ti = (t >> 4) << 2;
    const int tj = (t & 15) << 2;

    float acc[4][4];
#pragma unroll
    for (int r = 0; r < 4; ++r)
#pragma unroll
        for (int c = 0; c < 4; ++c) acc[r][c] = 0.0f;

    for (int k = 0; k < 64; k += 4) {
        float4 a[4], b[4];
#pragma unroll
        for (int r = 0; r < 4; ++r) a[r] = *(const float4*)(&As[ti + r][k]);
#pragma unroll
        for (int c = 0; c < 4; ++c) b[c] = *(const float4*)(&Bs[tj + c][k]);
#pragma unroll
        for (int r = 0; r < 4; ++r)
#pragma unroll
            for (int c = 0; c < 4; ++c) {
                float d0 = a[r].x - b[c].x;
                float d1 = a[r].y - b[c].y;
                float d2 = a[r].z - b[c].z;
                float d3 = a[r].w - b[c].w;
                float s = acc[r][c];
                s = fmaf(d0, d0, s);
                s = fmaf(d1, d1, s);
                s = fmaf(d2, d2, s);
                s = fmaf(d3, d3, s);
                acc[r][c] = s;
            }
    }

#pragma unroll
    for (int r = 0; r < 4; ++r) {
        int i = bi + ti + r;
        float4 v;
        float* vp = &v.x;
#pragma unroll
        for (int c = 0; c < 4; ++c) {
            int j = bj + tj + c;
            vp[c] = (i == j) ? INF : sqrtf(fmaxf(acc[r][c], 1e-12f));
        }
        *(float4*)(D + (size_t)i * N + (bj + tj)) = v;
    }
}

// ---------------------------------------------------------------------------
// Workgroup barrier that does NOT drain outstanding global loads (vmcnt).
// Publishes LDS (lgkmcnt(0)) then s_barrier. Speculative prefetches issued
// before this stay in flight across it; the backend inserts fine-grained
// vmcnt(N) at the actual register uses.
// ---------------------------------------------------------------------------
__device__ __forceinline__ void barrier_no_drain() {
    __asm__ __volatile__("s_waitcnt lgkmcnt(0)\n\ts_barrier" ::: "memory");
}

// ---------------------------------------------------------------------------
// Phase 2: thread t owns cols {1024q + 4t + l : q,l in 0..3} (per-instruction
// coalesced row loads). Exact argmin tie-break via u64 (valbits<<32|col) keys.
// Invariant: mind[c] == INF for all in-tree cols (maintained by masked fold).
// ---------------------------------------------------------------------------
__global__ __launch_bounds__(256) void prim_kernel(const float* __restrict__ D,
                                                   float* __restrict__ out) {
    __shared__ unsigned long long part[2][4];  // parity-double-buffered winners
    const int t = threadIdx.x;
    const int lane = t & 63;
    const int wv = t >> 6;

    float4 mind[4];
    const float4* r0 = (const float4*)D;
#pragma unroll
    for (int q = 0; q < 4; ++q) mind[q] = r0[t + 256 * q];  // row 0; D[0][0]=INF

    unsigned mask = (t == 0) ? 1u : 0u;  // col 0 = (q=0,l=0) of t=0
    float4 pre[4];                       // speculative row buffer
    int c2prev = -1;

    for (int s = 1; s < N; ++s) {
        // ---- local argmin with index (lowest col on ties) ----
        float v[16];
        int id[16];
#pragma unroll
        for (int q = 0; q < 4; ++q) {
            const float* p = (const float*)&mind[q];
#pragma unroll
            for (int l = 0; l < 4; ++l) {
                v[4 * q + l] = p[l];
                id[4 * q + l] = 4 * q + l;
            }
        }
#pragma unroll
        for (int st = 1; st < 16; st <<= 1)
#pragma unroll
            for (int i = 0; i < 16; i += 2 * st)
                if (v[i + st] < v[i]) {  // strict: keeps lower i (= lower col)
                    v[i] = v[i + st];
                    id[i] = id[i + st];
                }
        int lc = ((id[0] >> 2) << 10) | (t << 2) | (id[0] & 3);
        unsigned long long key =
            ((unsigned long long)__float_as_uint(v[0]) << 32) | (unsigned)lc;

        // ---- 64-lane u64 butterfly (exact value-then-col min) ----
#pragma unroll
        for (int off = 1; off < 64; off <<= 1) {
            unsigned long long o =
                (unsigned long long)__shfl_xor((long long)key, off, 64);
            if (o < key) key = o;
        }

        // ---- cross-wave combine: one no-drain barrier ----
        const int pb = s & 1;
        if (lane == 0) part[pb][wv] = key;
        barrier_no_drain();
        unsigned long long k0 = part[pb][0], k1 = part[pb][1];
        unsigned long long k2 = part[pb][2], k3 = part[pb][3];
        unsigned long long m01 = k0 < k1 ? k0 : k1, M01 = k0 < k1 ? k1 : k0;
        unsigned long long m23 = k2 < k3 ? k2 : k3, M23 = k2 < k3 ? k3 : k2;
        unsigned long long best = m01 < m23 ? m01 : m23;
        unsigned long long mxw = m01 < m23 ? M01 : M23;
        unsigned long long mnl = m01 < m23 ? m23 : m01;
        unsigned long long sec = mxw < mnl ? mxw : mnl;  // 2nd-best wave winner

        int j = __builtin_amdgcn_readfirstlane((int)(best & 0xffffffffULL));
        int r = __builtin_amdgcn_readfirstlane((int)(sec & 0xffffffffULL));
        unsigned dbits = (unsigned)(best >> 32);

        // ---- consume row j (spec hit -> issued a full step ago) ----
        float4 rowv[4];
        if (j == c2prev) {
#pragma unroll
            for (int q = 0; q < 4; ++q) rowv[q] = pre[q];
        } else {
            const float4* rp = (const float4*)(D + (size_t)(unsigned)j * N);
#pragma unroll
            for (int q = 0; q < 4; ++q) rowv[q] = rp[t + 256 * q];
        }
        // ---- re-speculate: runner-up row, stays in flight across barrier ----
        {
            const float4* sp = (const float4*)(D + (size_t)(unsigned)r * N);
#pragma unroll
            for (int q = 0; q < 4; ++q) pre[q] = sp[t + 256 * q];
            c2prev = r;
        }

        if (t == 0) {
            out[2 * (s - 1)] = 0.0f;
            out[2 * (s - 1) + 1] = __uint_as_float(dbits);
        }
        if (((j >> 2) & 255) == t)
            mask |= 1u << ((((unsigned)j >> 10) << 2) | (j & 3));

        // ---- masked fold: in-tree cols (incl. new j) pinned at INF ----
#pragma unroll
        for (int q = 0; q < 4; ++q) {
            float* mp = (float*)&mind[q];
            const float* rp2 = (const float*)&rowv[q];
#pragma unroll
            for (int l = 0; l < 4; ++l) {
                int i = 4 * q + l;
                float m = fminf(mp[l], rp2[l]);
                mp[l] = ((mask >> i) & 1u) ? INF : m;
            }
        }
    }
}

// ---------------------------------------------------------------------------
extern "C" void kernel_launch(void* const* d_in, const int* in_sizes, int n_in,
                              void* d_out, int out_size, void* d_ws, size_t ws_size,
                              hipStream_t stream) {
    const float* x = (const float*)d_in[0];
    float* D = (float*)d_ws;     // requires ws_size >= N*N*4 = 64 MiB
    float* out = (float*)d_out;  // [N-1][2]: (birth=0, death)

    dim3 grid(N / 64, N / 64);
    build_d_kernel<<<grid, 256, 0, stream>>>(x, D);
    prim_kernel<<<1, 256, 0, stream>>>(D, out);
}

// Round 5
// 4135.336 us; speedup vs baseline: 1.3599x; 1.1269x over previous
//
#include <hip/hip_runtime.h>
#include <math.h>

// RipsLayer: dim-0 persistence of Rips filtration on 4096 points in R^64.
// Phase 1: dense distance matrix D (64 MiB, in d_ws).
// Phase 2: exact Prim replay, 1 workgroup / 4 waves:
//   - DPP (row_shr/row_bcast) wave min-reduce + ballot index recovery
//     (blocked col ownership -> lowest lane == lowest col, exact ties)
//   - two-phase m1/m2 argmin: m1 over mind hides the row-j load latency;
//     straight-line loop (no spec branches) so vmcnt waits land late
//   - tree membership encoded as mind==INF (no mask bitfield)

#define N 4096
#define DF 64
#define INF __builtin_huge_valf()
#define INFBITS 0x7f800000u

// ---------------------------------------------------------------------------
// Phase 1: D[i][j] = sqrt(max(|x_i - x_j|^2, 1e-12)), diag = +inf.
// ---------------------------------------------------------------------------
__global__ __launch_bounds__(256) void build_d_kernel(const float* __restrict__ x,
                                                      float* __restrict__ D) {
    __shared__ float As[64][68];
    __shared__ float Bs[64][68];
    const int bi = blockIdx.y * 64;
    const int bj = blockIdx.x * 64;
    const int t = threadIdx.x;

#pragma unroll
    for (int g = 0; g < 4; ++g) {
        int idx = t + 256 * g;
        int row = idx >> 4;
        int k4 = (idx & 15) << 2;
        float4 va = *(const float4*)(x + (size_t)(bi + row) * DF + k4);
        float4 vb = *(const float4*)(x + (size_t)(bj + row) * DF + k4);
        *(float4*)(&As[row][k4]) = va;
        *(float4*)(&Bs[row][k4]) = vb;
    }
    __syncthreads();

    const int ti = (t >> 4) << 2;
    const int tj = (t & 15) << 2;

    float acc[4][4];
#pragma unroll
    for (int r = 0; r < 4; ++r)
#pragma unroll
        for (int c = 0; c < 4; ++c) acc[r][c] = 0.0f;

    for (int k = 0; k < 64; k += 4) {
        float4 a[4], b[4];
#pragma unroll
        for (int r = 0; r < 4; ++r) a[r] = *(const float4*)(&As[ti + r][k]);
#pragma unroll
        for (int c = 0; c < 4; ++c) b[c] = *(const float4*)(&Bs[tj + c][k]);
#pragma unroll
        for (int r = 0; r < 4; ++r)
#pragma unroll
            for (int c = 0; c < 4; ++c) {
                float d0 = a[r].x - b[c].x;
                float d1 = a[r].y - b[c].y;
                float d2 = a[r].z - b[c].z;
                float d3 = a[r].w - b[c].w;
                float s = acc[r][c];
                s = fmaf(d0, d0, s);
                s = fmaf(d1, d1, s);
                s = fmaf(d2, d2, s);
                s = fmaf(d3, d3, s);
                acc[r][c] = s;
            }
    }

#pragma unroll
    for (int r = 0; r < 4; ++r) {
        int i = bi + ti + r;
        float4 v;
        float* vp = &v.x;
#pragma unroll
        for (int c = 0; c < 4; ++c) {
            int j = bj + tj + c;
            vp[c] = (i == j) ? INF : sqrtf(fmaxf(acc[r][c], 1e-12f));
        }
        *(float4*)(D + (size_t)i * N + (bj + tj)) = v;
    }
}

// ---------------------------------------------------------------------------
// Barrier that publishes LDS (lgkmcnt) but leaves global loads in flight.
// ---------------------------------------------------------------------------
__device__ __forceinline__ void barrier_no_drain() {
    __asm__ __volatile__("s_waitcnt lgkmcnt(0)\n\ts_barrier" ::: "memory");
}

// ---------------------------------------------------------------------------
// Wave64 min via DPP: row_shr 1/2/4/8 then row_bcast 15/31; result in lane 63.
// update_dpp(old=INF,...) makes invalid source lanes contribute identity.
// ---------------------------------------------------------------------------
#define DPP_MIN_STEP(x, ctrl)                                                  \
    x = fminf(x, __int_as_float(__builtin_amdgcn_update_dpp(                   \
                     0x7f800000, __float_as_int(x), ctrl, 0xF, 0xF, false)))

__device__ __forceinline__ float wave_min_f32_l63(float x) {
    DPP_MIN_STEP(x, 0x111);  // row_shr:1
    DPP_MIN_STEP(x, 0x112);  // row_shr:2
    DPP_MIN_STEP(x, 0x114);  // row_shr:4
    DPP_MIN_STEP(x, 0x118);  // row_shr:8
    DPP_MIN_STEP(x, 0x142);  // row_bcast:15
    DPP_MIN_STEP(x, 0x143);  // row_bcast:31
    return x;                // lane 63 = wave min
}

// lv/lcol: this lane's local min value and its (lowest) column. Ownership is
// blocked (lane owns cols [16t,16t+16)), so among tied lanes the lowest lane
// holds the lowest column -> exact jnp.argmin first-index semantics.
__device__ __forceinline__ unsigned long long wave_argmin_key(float lv, int lcol) {
    float red = wave_min_f32_l63(lv);
    float wm = __int_as_float(__builtin_amdgcn_readlane(__float_as_int(red), 63));
    unsigned long long tied = __ballot(lv == wm);
    int src = __ffsll(tied) - 1;
    int wcol = __builtin_amdgcn_readlane(lcol, src);
    return ((unsigned long long)__float_as_uint(wm) << 32) | (unsigned)wcol;
}

// Local argmin over 16 values with exact lowest-index tie-break.
__device__ __forceinline__ void local_argmin16(const float* __restrict__ a,
                                               float& bv, int& bi) {
    float v[16];
    int id[16];
#pragma unroll
    for (int i = 0; i < 16; ++i) { v[i] = a[i]; id[i] = i; }
#pragma unroll
    for (int st = 1; st < 16; st <<= 1)
#pragma unroll
        for (int i = 0; i < 16; i += 2 * st)
            if (v[i + st] < v[i]) {  // strict: keep lower index on ties
                v[i] = v[i + st];
                id[i] = id[i + st];
            }
    bv = v[0];
    bi = id[0];
}

// ---------------------------------------------------------------------------
// Phase 2. Invariant: mv[i] == INF  <=>  col (16t+i) is in the tree.
// ---------------------------------------------------------------------------
__global__ __launch_bounds__(256) void prim_kernel(const float* __restrict__ D,
                                                   float* __restrict__ out) {
    __shared__ __align__(16) unsigned long long part[2][4];
    const int t = threadIdx.x;
    const int lane = t & 63;
    const int wv = t >> 6;

    float mv[16];  // mind, pinned INF at tree cols
    float rv[16];  // row of last-selected vertex (in flight across backedge)
    {
        const float4* rp0 = (const float4*)(D + 16 * t);  // row 0; D[0][0]=INF
#pragma unroll
        for (int q = 0; q < 4; ++q) {
            float4 a = rp0[q];
            mv[4 * q + 0] = a.x; mv[4 * q + 1] = a.y;
            mv[4 * q + 2] = a.z; mv[4 * q + 3] = a.w;
        }
#pragma unroll
        for (int i = 0; i < 16; ++i) rv[i] = mv[i];  // "row of vertex 0"
    }

#pragma unroll 1
    for (int s = 1; s < N; ++s) {
        // ---- m1: argmin over mind (no dependence on the in-flight row) ----
        float bv1;
        int bi1;
        local_argmin16(mv, bv1, bi1);
        unsigned long long key1 = wave_argmin_key(bv1, 16 * t + bi1);

        // ---- m2: argmin over the arrived row, tree cols masked to INF ----
        float mr[16];
#pragma unroll
        for (int i = 0; i < 16; ++i)
            mr[i] = (__float_as_uint(mv[i]) == INFBITS) ? INF : rv[i];
        float bv2;
        int bi2;
        local_argmin16(mr, bv2, bi2);
        unsigned long long key2 = wave_argmin_key(bv2, 16 * t + bi2);

        unsigned long long kw = key1 < key2 ? key1 : key2;
        const int pb = s & 1;
        if (lane == 0) part[pb][wv] = kw;
        barrier_no_drain();

        const ulonglong2* pp = (const ulonglong2*)&part[pb][0];
        ulonglong2 ab = pp[0], cd = pp[1];
        unsigned long long b0 = ab.x < ab.y ? ab.x : ab.y;
        unsigned long long b1 = cd.x < cd.y ? cd.x : cd.y;
        unsigned long long best = b0 < b1 ? b0 : b1;
        int j = __builtin_amdgcn_readfirstlane((int)(best & 0xffffffffULL));
        int dbits = __builtin_amdgcn_readfirstlane((int)(best >> 32));

        // ---- issue next row load immediately (consumed next iter in m2) ----
        const float4* rp = (const float4*)(D + (size_t)(unsigned)j * N + 16 * t);
        float4 n0 = rp[0], n1 = rp[1], n2 = rp[2], n3 = rp[3];

        if (t == 0) {
            out[2 * (s - 1)] = 0.0f;
            out[2 * (s - 1) + 1] = __uint_as_float((unsigned)dbits);
        }

        // ---- fold (mind = min(mind, maskedR)) + pin newly-added col j ----
        unsigned jl = (unsigned)j & 15u;
        unsigned jt = (unsigned)j >> 4;
        bool mine = ((unsigned)t == jt);
#pragma unroll
        for (int i = 0; i < 16; ++i) {
            float m = fminf(mv[i], mr[i]);
            mv[i] = (mine && ((unsigned)i == jl)) ? INF : m;
        }

        // ---- carry the new row ----
        rv[0] = n0.x;  rv[1] = n0.y;  rv[2] = n0.z;  rv[3] = n0.w;
        rv[4] = n1.x;  rv[5] = n1.y;  rv[6] = n1.z;  rv[7] = n1.w;
        rv[8] = n2.x;  rv[9] = n2.y;  rv[10] = n2.z; rv[11] = n2.w;
        rv[12] = n3.x; rv[13] = n3.y; rv[14] = n3.z; rv[15] = n3.w;
    }
}

// ---------------------------------------------------------------------------
extern "C" void kernel_launch(void* const* d_in, const int* in_sizes, int n_in,
                              void* d_out, int out_size, void* d_ws, size_t ws_size,
                              hipStream_t stream) {
    const float* x = (const float*)d_in[0];
    float* D = (float*)d_ws;     // requires ws_size >= N*N*4 = 64 MiB
    float* out = (float*)d_out;  // [N-1][2]: (birth=0, death)

    dim3 grid(N / 64, N / 64);
    build_d_kernel<<<grid, 256, 0, stream>>>(x, D);
    prim_kernel<<<1, 256, 0, stream>>>(D, out);
}